// Round 18
// baseline (463.812 us; speedup 1.0000x reference)
//
#include <hip/hip_runtime.h>

typedef unsigned short u16;
typedef __attribute__((ext_vector_type(8))) short s8frag;   // 8 bf16 (4 VGPRs)
typedef __attribute__((ext_vector_type(4))) float f32x4;    // MFMA accumulator

#define GLOAD16(gp, lp)                                                        \
  __builtin_amdgcn_global_load_lds(                                            \
      (const __attribute__((address_space(1))) void*)(gp),                     \
      (__attribute__((address_space(3))) void*)(lp), 16, 0, 0)

__device__ __forceinline__ u16 f2bf(float x) {
  unsigned int u = __float_as_uint(x);
  unsigned int r = (u + 0x7fffu + ((u >> 16) & 1u)) >> 16;  // RNE
  return (u16)r;
}

// ---------------------------------------------------------------------------
// Kernel 1 (merged builders + weight prep):
//   z < 16 : img multi-level sum (upsample-by-(n+1) lvl>0, edge-pad to 256)
//   z 16-31: pts transpose (float4 loads)
//   z == 32: BN-fold weight prep for both branches (2 elems/thread)
// img/pts write TRANSPOSED bf16 dst[n][hw][c]; bodies verbatim round-9.
// ---------------------------------------------------------------------------
__global__ __launch_bounds__(256) void build_b(
    const float* __restrict__ f0, const float* __restrict__ f1,
    const float* __restrict__ f2, const float* __restrict__ f3,
    const float* __restrict__ f4, const float* __restrict__ pts,
    const float* __restrict__ wi, const float* __restrict__ bi,
    const float* __restrict__ gi, const float* __restrict__ bei,
    const float* __restrict__ mi, const float* __restrict__ vi,
    const float* __restrict__ wp, const float* __restrict__ bp,
    const float* __restrict__ gp, const float* __restrict__ bep,
    const float* __restrict__ mp, const float* __restrict__ vp,
    u16* __restrict__ Bimg, u16* __restrict__ Bpts,
    u16* __restrict__ wA_img, float* __restrict__ bias_i,
    u16* __restrict__ wA_pts, float* __restrict__ bias_p) {
  int t = threadIdx.x;
  int z = blockIdx.z;             // 0..32

  if (z == 32) {                  // ---- weight prep plane ----
    int base = ((blockIdx.y * 4 + blockIdx.x) * 256 + t) * 2;
#pragma unroll
    for (int e = 0; e < 2; ++e) {
      int gidx = base + e;        // 0 .. 2*512*512-1
      int branch = gidx >> 18;
      int idx = gidx & ((1 << 18) - 1);
      int o = idx >> 9, c = idx & 511;
      const float* w = branch ? wp : wi;
      const float* b = branch ? bp : bi;
      const float* g = branch ? gp : gi;
      const float* be = branch ? bep : bei;
      const float* mn = branch ? mp : mi;
      const float* vr = branch ? vp : vi;
      u16* wo = branch ? wA_pts : wA_img;
      float* bo = branch ? bias_p : bias_i;
      float scale = g[o] * rsqrtf(vr[o] + 1e-5f);
      wo[idx] = f2bf(w[idx] * scale);
      if (c == 0) bo[o] = scale * (b[o] - mn[o]) + be[o];
    }
    return;
  }

  __shared__ float tile[64][65];
  int wblk = blockIdx.x;          // 0..3
  int h = blockIdx.y;             // 0..255
  bool is_img = z < 16;
  int zz = is_img ? z : z - 16;
  int n = zz >> 3;                // 0..1
  int cblk = zz & 7;              // 0..7
  int cbase = cblk * 64;

  if (is_img) {
    int wl = t & 63, w = wblk * 64 + wl;
    const float* feats[5] = {f0, f1, f2, f3, f4};
    const int S[5] = {128, 64, 32, 16, 8};
    int off[5];
#pragma unroll
    for (int l = 0; l < 5; ++l) {
      int s = S[l];
      int scale = (n == 1 && l > 0) ? 2 : 1;
      int u = s * scale, pad = (256 - u) >> 1;
      int ih = h - pad; ih = ih < 0 ? 0 : (ih > u - 1 ? u - 1 : ih); ih /= scale;
      int iw = w - pad; iw = iw < 0 ? 0 : (iw > u - 1 ? u - 1 : iw); iw /= scale;
      off[l] = ih * s + iw;
    }
    for (int cs = 0; cs < 16; ++cs) {
      int cl = cs * 4 + (t >> 6);
      int c = cbase + cl;
      float acc = 0.f;
#pragma unroll
      for (int l = 0; l < 5; ++l) {
        int s = S[l];
        acc += feats[l][(long)(n * 512 + c) * s * s + off[l]];
      }
      tile[cl][wl] = acc;
    }
  } else {
    int wq = t & 15;     // w-quad within 64
    int cl0 = t >> 4;    // 0..15
#pragma unroll
    for (int j = 0; j < 4; ++j) {
      int cl = cl0 + j * 16;
      int c = cbase + cl;
      float4 v = *(const float4*)&pts[((long)(n * 512 + c) * 256 + h) * 256 +
                                      wblk * 64 + wq * 4];
      tile[cl][wq * 4 + 0] = v.x;
      tile[cl][wq * 4 + 1] = v.y;
      tile[cl][wq * 4 + 2] = v.z;
      tile[cl][wq * 4 + 3] = v.w;
    }
  }
  __syncthreads();

  u16* dst = is_img ? Bimg : Bpts;
  long hwb = (long)h * 256 + wblk * 64;
#pragma unroll
  for (int half = 0; half < 2; ++half) {
    int c0 = (t & 7) * 8;
    int wl2 = half * 32 + (t >> 3);
    u16 p[8];
#pragma unroll
    for (int j = 0; j < 8; ++j) p[j] = f2bf(tile[c0 + j][wl2]);
    long di = ((long)n * 65536 + hwb + wl2) * 512 + cbase + c0;
    *(uint4*)(dst + di) = *(const uint4*)p;
  }
}

// ---------------------------------------------------------------------------
// Kernel 2: 256x256-TILE GEMM (round-15/17 base) with SWAPPED MFMA OPERANDS:
// acc = mfma(b_frag, a_frag, acc) -> D = [hw][o] fragment layout, so each
// lane's 4 acc regs are 4 CONSECUTIVE hw at fixed o -> epilogue packs them
// into ONE global_store_dwordx4 (16 store instrs/thread instead of 64,
// 64B-contiguous segments instead of 4x64B scatter). LDS reads, staging,
// swizzle byte-identical to round 15/17 (proven). Ring-3, vmcnt(2),
// one barrier/step. Grid: (1024 = 2rt x 512ct XCD-chunked, 1, 2 branches).
// ---------------------------------------------------------------------------
__global__ __launch_bounds__(1024, 1) void gemm_fused(
    const u16* __restrict__ Aimg, const u16* __restrict__ Apts,
    const u16* __restrict__ Bimg, const u16* __restrict__ Bpts,
    const float* __restrict__ biasImg, const float* __restrict__ biasPts,
    float* __restrict__ out) {
  int br = blockIdx.z;
  const u16* A = br ? Apts : Aimg;
  const u16* B = br ? Bpts : Bimg;
  const float* bias = br ? biasPts : biasImg;

  // bijective XCD chunk swizzle: 1024 wgs, 8 XCDs, 128 per XCD; rt fastest
  int s = blockIdx.x;
  int w = (s & 7) * 128 + (s >> 3);
  int rt = w & 1;                      // row tile 0..1 (adjacent on one XCD)
  int ct = w >> 1;                     // col tile 0..511
  int n = ct >> 8;                     // sample
  int colbase = (ct & 255) * 256;      // hw base within sample
  const u16* Bn = B + ((long)n * 65536) * 512;

  __shared__ u16 As[3][256 * 32];      // 48 KiB
  __shared__ u16 Bs[3][256 * 32];      // 48 KiB

  int t = threadIdx.x;
  int wave = t >> 6, lane = t & 63;
  int wr = wave >> 2, wc = wave & 3;   // 4M x 4N wave grid
  int lrow = lane & 15;
  int q = lane >> 4;                   // k-chunk 0..3 (16B chunks)

  f32x4 acc[4][4] = {};

  // per-thread staging slot: row = t>>2 (0..255), kp = t&3
#define STAGE(buf, kt_)                                                       \
  {                                                                           \
    int kk_ = (kt_) * 32;                                                     \
    int row = t >> 2, kp = t & 3;                                             \
    int sw = (row >> 1) & 3;                                                  \
    GLOAD16(A + ((long)(rt * 256 + row) * 512 + kk_ + ((kp ^ sw) * 8)),       \
            &As[buf][(t) * 8]);                                               \
    GLOAD16(Bn + ((long)(colbase + row) * 512 + kk_ + ((kp ^ sw) * 8)),       \
            &Bs[buf][(t) * 8]);                                               \
  }

  // prologue: stages 0,1 in flight (4 loads/thread); vmcnt(2) retires stage 0
  STAGE(0, 0);
  STAGE(1, 1);
  asm volatile("s_waitcnt vmcnt(2)" ::: "memory");
  __builtin_amdgcn_s_barrier();

#pragma unroll 1
  for (int kt = 0; kt < 16; ++kt) {
    int cur = kt % 3;
    s8frag a[4], b[4];
#pragma unroll
    for (int m = 0; m < 4; ++m) {
      int r = wr * 64 + m * 16 + lrow;
      a[m] = *(const s8frag*)&As[cur][r * 32 + ((q ^ ((r >> 1) & 3)) * 8)];
    }
#pragma unroll
    for (int nn = 0; nn < 4; ++nn) {
      int r = wc * 64 + nn * 16 + lrow;
      b[nn] = *(const s8frag*)&Bs[cur][r * 32 + ((q ^ ((r >> 1) & 3)) * 8)];
    }
    if (kt < 14) STAGE((kt + 2) % 3, kt + 2);   // 2-step issue lead
    __builtin_amdgcn_s_setprio(1);
    // SWAPPED operands: "A"-matrix = hw-rows tile (b), "B"-matrix = o-cols
    // tile (a) -> D[hw][o]: lane holds hw=(lane>>4)*4+j (consecutive!), o=lane&15.
#pragma unroll
    for (int m = 0; m < 4; ++m)
#pragma unroll
      for (int nn = 0; nn < 4; ++nn)
        acc[m][nn] =
            __builtin_amdgcn_mfma_f32_16x16x32_bf16(b[nn], a[m], acc[m][nn], 0, 0, 0);
    __builtin_amdgcn_s_setprio(0);
    if (kt < 15) {
      if (kt < 14)
        asm volatile("s_waitcnt vmcnt(2)" ::: "memory");
      else
        asm volatile("s_waitcnt vmcnt(0)" ::: "memory");
      __builtin_amdgcn_s_barrier();
    }
  }
#undef STAGE

  // epilogue: bias + relu, ONE dwordx4 store per (m,nn): 16B contiguous hw
  long outbase = ((long)n * 1024 + br * 512) * 65536;
#pragma unroll
  for (int m = 0; m < 4; ++m) {
    int o = rt * 256 + wr * 64 + m * 16 + lrow;
    float bv = bias[o];
    long orow = outbase + (long)o * 65536;
#pragma unroll
    for (int nn = 0; nn < 4; ++nn) {
      int hwq = colbase + wc * 64 + nn * 16 + q * 4;
      f32x4 v;
#pragma unroll
      for (int j = 0; j < 4; ++j) {
        float x = acc[m][nn][j] + bv;
        v[j] = x > 0.f ? x : 0.f;
      }
      *(f32x4*)(out + orow + hwq) = v;
    }
  }
}

// ---------------------------------------------------------------------------
extern "C" void kernel_launch(void* const* d_in, const int* in_sizes, int n_in,
                              void* d_out, int out_size, void* d_ws,
                              size_t ws_size, hipStream_t stream) {
  (void)in_sizes; (void)n_in; (void)out_size; (void)ws_size;
  const float* f0 = (const float*)d_in[0];
  const float* f1 = (const float*)d_in[1];
  const float* f2 = (const float*)d_in[2];
  const float* f3 = (const float*)d_in[3];
  const float* f4 = (const float*)d_in[4];
  const float* pts = (const float*)d_in[5];
  const float* img_w = (const float*)d_in[6];
  const float* img_b = (const float*)d_in[7];
  const float* img_gamma = (const float*)d_in[8];
  const float* img_beta = (const float*)d_in[9];
  const float* img_mean = (const float*)d_in[10];
  const float* img_var = (const float*)d_in[11];
  const float* pts_w = (const float*)d_in[12];
  const float* pts_b = (const float*)d_in[13];
  const float* pts_gamma = (const float*)d_in[14];
  const float* pts_beta = (const float*)d_in[15];
  const float* pts_mean = (const float*)d_in[16];
  const float* pts_var = (const float*)d_in[17];

  char* ws = (char*)d_ws;
  u16* wA_img = (u16*)ws;                          // 512 KiB
  u16* wA_pts = wA_img + 512 * 512;                // 512 KiB
  float* bias_img = (float*)(ws + (1u << 20));
  float* bias_pts = bias_img + 512;
  u16* Bimg = (u16*)(ws + (2u << 20));             // 128 MiB  [n][hw][c]
  u16* Bpts = Bimg + (size_t)2 * 65536 * 512;      // 128 MiB

  build_b<<<dim3(4, 256, 33), 256, 0, stream>>>(
      f0, f1, f2, f3, f4, pts, img_w, img_b, img_gamma, img_beta, img_mean,
      img_var, pts_w, pts_b, pts_gamma, pts_beta, pts_mean, pts_var, Bimg,
      Bpts, wA_img, bias_img, wA_pts, bias_pts);
  gemm_fused<<<dim3(1024, 1, 2), 1024, 0, stream>>>(
      wA_img, wA_pts, Bimg, Bpts, bias_img, bias_pts, (float*)d_out);
}

// Round 19
// 405.633 us; speedup vs baseline: 1.1434x; 1.1434x over previous
//
#include <hip/hip_runtime.h>

typedef unsigned short u16;
typedef __attribute__((ext_vector_type(8))) short s8frag;   // 8 bf16 (4 VGPRs)
typedef __attribute__((ext_vector_type(4))) float f32x4;    // MFMA accumulator

#define GLOAD16(gp, lp)                                                        \
  __builtin_amdgcn_global_load_lds(                                            \
      (const __attribute__((address_space(1))) void*)(gp),                     \
      (__attribute__((address_space(3))) void*)(lp), 16, 0, 0)

__device__ __forceinline__ u16 f2bf(float x) {
  unsigned int u = __float_as_uint(x);
  unsigned int r = (u + 0x7fffu + ((u >> 16) & 1u)) >> 16;  // RNE
  return (u16)r;
}

// ---------------------------------------------------------------------------
// Kernel 1 (merged builders + weight prep):
//   z < 16 : img multi-level sum -- REGISTER-DIRECT: each thread sums its own
//            8-c chunk (same 80 gather loads), cvt to bf16 immediately, then
//            bounces through an 8-KiB bf16 tile (XOR chunk slot: write
//            [w][chunk^(w&7)], read [w][kcl^(w&7)] -- both conflict-free)
//            for the same coalesced 128B-segment stores. Removes the fp32
//            LDS round-trip (~15% instrs, 4x LDS traffic).
//   z 16-31: pts transpose (float4 loads) -- unchanged (proven).
//   z == 32: BN-fold weight prep -- unchanged.
// ---------------------------------------------------------------------------
__global__ __launch_bounds__(256) void build_b(
    const float* __restrict__ f0, const float* __restrict__ f1,
    const float* __restrict__ f2, const float* __restrict__ f3,
    const float* __restrict__ f4, const float* __restrict__ pts,
    const float* __restrict__ wi, const float* __restrict__ bi,
    const float* __restrict__ gi, const float* __restrict__ bei,
    const float* __restrict__ mi, const float* __restrict__ vi,
    const float* __restrict__ wp, const float* __restrict__ bp,
    const float* __restrict__ gp, const float* __restrict__ bep,
    const float* __restrict__ mp, const float* __restrict__ vp,
    u16* __restrict__ Bimg, u16* __restrict__ Bpts,
    u16* __restrict__ wA_img, float* __restrict__ bias_i,
    u16* __restrict__ wA_pts, float* __restrict__ bias_p) {
  int t = threadIdx.x;
  int z = blockIdx.z;             // 0..32

  if (z == 32) {                  // ---- weight prep plane ----
    int base = ((blockIdx.y * 4 + blockIdx.x) * 256 + t) * 2;
#pragma unroll
    for (int e = 0; e < 2; ++e) {
      int gidx = base + e;        // 0 .. 2*512*512-1
      int branch = gidx >> 18;
      int idx = gidx & ((1 << 18) - 1);
      int o = idx >> 9, c = idx & 511;
      const float* w = branch ? wp : wi;
      const float* b = branch ? bp : bi;
      const float* g = branch ? gp : gi;
      const float* be = branch ? bep : bei;
      const float* mn = branch ? mp : mi;
      const float* vr = branch ? vp : vi;
      u16* wo = branch ? wA_pts : wA_img;
      float* bo = branch ? bias_p : bias_i;
      float scale = g[o] * rsqrtf(vr[o] + 1e-5f);
      wo[idx] = f2bf(w[idx] * scale);
      if (c == 0) bo[o] = scale * (b[o] - mn[o]) + be[o];
    }
    return;
  }

  int wblk = blockIdx.x;          // 0..3
  int h = blockIdx.y;             // 0..255
  bool is_img = z < 16;
  int zz = is_img ? z : z - 16;
  int n = zz >> 3;                // 0..1
  int cblk = zz & 7;              // 0..7
  int cbase = cblk * 64;

  if (is_img) {
    // ---- img: register-direct gather-sum, bf16 LDS bounce ----
    __shared__ u16 btile[64][8][8];   // [w][chunk-slot][8c] = 8 KiB
    int wl = t & 63, w = wblk * 64 + wl;
    int cg = t >> 6;                  // chunk group 0..3
    const float* feats[5] = {f0, f1, f2, f3, f4};
    const int S[5] = {128, 64, 32, 16, 8};
    long gbase[5];
#pragma unroll
    for (int l = 0; l < 5; ++l) {
      int sl = S[l];
      int sh = (n == 1 && l > 0) ? 1 : 0;
      int u = sl << sh, pad = (256 - u) >> 1;
      int ih = h - pad; ih = ih < 0 ? 0 : (ih > u - 1 ? u - 1 : ih); ih >>= sh;
      int iw = w - pad; iw = iw < 0 ? 0 : (iw > u - 1 ? u - 1 : iw); iw >>= sh;
      gbase[l] = (long)(n * 512) * sl * sl + ih * sl + iw;
    }
#pragma unroll
    for (int it = 0; it < 2; ++it) {
      int chunk = cg + it * 4;        // 0..7
      int c0 = cbase + chunk * 8;
      u16 pk[8];
#pragma unroll
      for (int j = 0; j < 8; ++j) {
        int c = c0 + j;
        float a_ = 0.f;
#pragma unroll
        for (int l = 0; l < 5; ++l)
          a_ += feats[l][gbase[l] + (long)c * (S[l] * S[l])];
        pk[j] = f2bf(a_);
      }
      *(uint4*)&btile[wl][chunk ^ (wl & 7)][0] = *(const uint4*)pk;
    }
    __syncthreads();
#pragma unroll
    for (int half = 0; half < 2; ++half) {
      int w2 = half * 32 + (t >> 3);  // 0..63
      int kcl = t & 7;                // chunk 0..7
      uint4 v = *(const uint4*)&btile[w2][kcl ^ (w2 & 7)][0];
      long di = ((long)n * 65536 + (long)h * 256 + wblk * 64 + w2) * 512 +
                cbase + kcl * 8;
      *(uint4*)(Bimg + di) = v;
    }
    return;
  }

  // ---- pts: float4-load LDS transpose (round-9 proven, unchanged) ----
  __shared__ float tile[64][65];
  int wq = t & 15;     // w-quad within 64
  int cl0 = t >> 4;    // 0..15
#pragma unroll
  for (int j = 0; j < 4; ++j) {
    int cl = cl0 + j * 16;
    int c = cbase + cl;
    float4 v = *(const float4*)&pts[((long)(n * 512 + c) * 256 + h) * 256 +
                                    wblk * 64 + wq * 4];
    tile[cl][wq * 4 + 0] = v.x;
    tile[cl][wq * 4 + 1] = v.y;
    tile[cl][wq * 4 + 2] = v.z;
    tile[cl][wq * 4 + 3] = v.w;
  }
  __syncthreads();

  long hwb = (long)h * 256 + wblk * 64;
#pragma unroll
  for (int half = 0; half < 2; ++half) {
    int c0 = (t & 7) * 8;
    int wl2 = half * 32 + (t >> 3);
    u16 p[8];
#pragma unroll
    for (int j = 0; j < 8; ++j) p[j] = f2bf(tile[c0 + j][wl2]);
    long di = ((long)n * 65536 + hwb + wl2) * 512 + cbase + c0;
    *(uint4*)(Bpts + di) = *(const uint4*)p;
  }
}

// ---------------------------------------------------------------------------
// Kernel 2: 256x256-TILE GEMM (round-15/17/18 proven, FROZEN). Swapped MFMA
// operands -> D=[hw][o], dwordx4 epilogue stores. Ring-3 LDS (96 KiB),
// counted vmcnt(2), one barrier/step, XOR swizzle, XCD-chunked grid.
// ---------------------------------------------------------------------------
__global__ __launch_bounds__(1024, 1) void gemm_fused(
    const u16* __restrict__ Aimg, const u16* __restrict__ Apts,
    const u16* __restrict__ Bimg, const u16* __restrict__ Bpts,
    const float* __restrict__ biasImg, const float* __restrict__ biasPts,
    float* __restrict__ out) {
  int br = blockIdx.z;
  const u16* A = br ? Apts : Aimg;
  const u16* B = br ? Bpts : Bimg;
  const float* bias = br ? biasPts : biasImg;

  // bijective XCD chunk swizzle: 1024 wgs, 8 XCDs, 128 per XCD; rt fastest
  int s = blockIdx.x;
  int w = (s & 7) * 128 + (s >> 3);
  int rt = w & 1;                      // row tile 0..1 (adjacent on one XCD)
  int ct = w >> 1;                     // col tile 0..511
  int n = ct >> 8;                     // sample
  int colbase = (ct & 255) * 256;      // hw base within sample
  const u16* Bn = B + ((long)n * 65536) * 512;

  __shared__ u16 As[3][256 * 32];      // 48 KiB
  __shared__ u16 Bs[3][256 * 32];      // 48 KiB

  int t = threadIdx.x;
  int wave = t >> 6, lane = t & 63;
  int wr = wave >> 2, wc = wave & 3;   // 4M x 4N wave grid
  int lrow = lane & 15;
  int q = lane >> 4;                   // k-chunk 0..3 (16B chunks)

  f32x4 acc[4][4] = {};

  // per-thread staging slot: row = t>>2 (0..255), kp = t&3
#define STAGE(buf, kt_)                                                       \
  {                                                                           \
    int kk_ = (kt_) * 32;                                                     \
    int row = t >> 2, kp = t & 3;                                             \
    int sw = (row >> 1) & 3;                                                  \
    GLOAD16(A + ((long)(rt * 256 + row) * 512 + kk_ + ((kp ^ sw) * 8)),       \
            &As[buf][(t) * 8]);                                               \
    GLOAD16(Bn + ((long)(colbase + row) * 512 + kk_ + ((kp ^ sw) * 8)),       \
            &Bs[buf][(t) * 8]);                                               \
  }

  // prologue: stages 0,1 in flight (4 loads/thread); vmcnt(2) retires stage 0
  STAGE(0, 0);
  STAGE(1, 1);
  asm volatile("s_waitcnt vmcnt(2)" ::: "memory");
  __builtin_amdgcn_s_barrier();

#pragma unroll 1
  for (int kt = 0; kt < 16; ++kt) {
    int cur = kt % 3;
    s8frag a[4], b[4];
#pragma unroll
    for (int m = 0; m < 4; ++m) {
      int r = wr * 64 + m * 16 + lrow;
      a[m] = *(const s8frag*)&As[cur][r * 32 + ((q ^ ((r >> 1) & 3)) * 8)];
    }
#pragma unroll
    for (int nn = 0; nn < 4; ++nn) {
      int r = wc * 64 + nn * 16 + lrow;
      b[nn] = *(const s8frag*)&Bs[cur][r * 32 + ((q ^ ((r >> 1) & 3)) * 8)];
    }
    if (kt < 14) STAGE((kt + 2) % 3, kt + 2);   // 2-step issue lead
    __builtin_amdgcn_s_setprio(1);
    // SWAPPED operands -> D[hw][o]: lane holds 4 consecutive hw at fixed o.
#pragma unroll
    for (int m = 0; m < 4; ++m)
#pragma unroll
      for (int nn = 0; nn < 4; ++nn)
        acc[m][nn] =
            __builtin_amdgcn_mfma_f32_16x16x32_bf16(b[nn], a[m], acc[m][nn], 0, 0, 0);
    __builtin_amdgcn_s_setprio(0);
    if (kt < 15) {
      if (kt < 14)
        asm volatile("s_waitcnt vmcnt(2)" ::: "memory");
      else
        asm volatile("s_waitcnt vmcnt(0)" ::: "memory");
      __builtin_amdgcn_s_barrier();
    }
  }
#undef STAGE

  // epilogue: bias + relu, ONE dwordx4 store per (m,nn): 16B contiguous hw
  long outbase = ((long)n * 1024 + br * 512) * 65536;
#pragma unroll
  for (int m = 0; m < 4; ++m) {
    int o = rt * 256 + wr * 64 + m * 16 + lrow;
    float bv = bias[o];
    long orow = outbase + (long)o * 65536;
#pragma unroll
    for (int nn = 0; nn < 4; ++nn) {
      int hwq = colbase + wc * 64 + nn * 16 + q * 4;
      f32x4 v;
#pragma unroll
      for (int j = 0; j < 4; ++j) {
        float x = acc[m][nn][j] + bv;
        v[j] = x > 0.f ? x : 0.f;
      }
      *(f32x4*)(out + orow + hwq) = v;
    }
  }
}

// ---------------------------------------------------------------------------
extern "C" void kernel_launch(void* const* d_in, const int* in_sizes, int n_in,
                              void* d_out, int out_size, void* d_ws,
                              size_t ws_size, hipStream_t stream) {
  (void)in_sizes; (void)n_in; (void)out_size; (void)ws_size;
  const float* f0 = (const float*)d_in[0];
  const float* f1 = (const float*)d_in[1];
  const float* f2 = (const float*)d_in[2];
  const float* f3 = (const float*)d_in[3];
  const float* f4 = (const float*)d_in[4];
  const float* pts = (const float*)d_in[5];
  const float* img_w = (const float*)d_in[6];
  const float* img_b = (const float*)d_in[7];
  const float* img_gamma = (const float*)d_in[8];
  const float* img_beta = (const float*)d_in[9];
  const float* img_mean = (const float*)d_in[10];
  const float* img_var = (const float*)d_in[11];
  const float* pts_w = (const float*)d_in[12];
  const float* pts_b = (const float*)d_in[13];
  const float* pts_gamma = (const float*)d_in[14];
  const float* pts_beta = (const float*)d_in[15];
  const float* pts_mean = (const float*)d_in[16];
  const float* pts_var = (const float*)d_in[17];

  char* ws = (char*)d_ws;
  u16* wA_img = (u16*)ws;                          // 512 KiB
  u16* wA_pts = wA_img + 512 * 512;                // 512 KiB
  float* bias_img = (float*)(ws + (1u << 20));
  float* bias_pts = bias_img + 512;
  u16* Bimg = (u16*)(ws + (2u << 20));             // 128 MiB  [n][hw][c]
  u16* Bpts = Bimg + (size_t)2 * 65536 * 512;      // 128 MiB

  build_b<<<dim3(4, 256, 33), 256, 0, stream>>>(
      f0, f1, f2, f3, f4, pts, img_w, img_b, img_gamma, img_beta, img_mean,
      img_var, pts_w, pts_b, pts_gamma, pts_beta, pts_mean, pts_var, Bimg,
      Bpts, wA_img, bias_img, wA_pts, bias_pts);
  gemm_fused<<<dim3(1024, 1, 2), 1024, 0, stream>>>(
      wA_img, wA_pts, Bimg, Bpts, bias_img, bias_pts, (float*)d_out);
}